// Round 5
// baseline (643.573 us; speedup 1.0000x reference)
//
#include <hip/hip_runtime.h>
#include <hip/hip_bf16.h>
#include <hip/hip_fp16.h>
#include <math.h>

#define N_NODES 50000
#define N_EDGES 800000
#define ET      (N_EDGES + N_NODES)   // with self loops
#define IN_DIM  128
#define HEADS   4
#define HID     64
#define HC      256                   // HEADS*HID
#define OUTD    128
#define NB_SCAN 98                    // ceil(N_NODES/512)

typedef _Float16 half8 __attribute__((ext_vector_type(8)));
typedef float f32x4 __attribute__((ext_vector_type(4)));

// ---------------- fused setup: hist + x->fp16 + W transposes + zero S2/D2 ----

#define J_HIST  ET                       // 850000
#define J_CVT   (N_NODES * IN_DIM / 4)   // 1600000
#define J_W     131072
#define SETUP_TOTAL (J_HIST + J_CVT + J_W + 2 * N_NODES)

__global__ void setup_k(const int* __restrict__ ei, int* __restrict__ counts,
                        const float* __restrict__ x, __half* __restrict__ xh,
                        const float* __restrict__ W0, __half* __restrict__ Wt0,
                        const float* __restrict__ W1, __half* __restrict__ Wt1,
                        const float* __restrict__ W2, __half* __restrict__ Wt2,
                        float* __restrict__ S2, float* __restrict__ D2) {
    int g = blockIdx.x * 256 + threadIdx.x;
    if (g < J_HIST) {
        int dv = (g < N_EDGES) ? ei[N_EDGES + g] : (g - N_EDGES);
        atomicAdd(&counts[dv], 1);
        return;
    }
    g -= J_HIST;
    if (g < J_CVT) {
        float4 v = *(const float4*)(x + (size_t)g * 4);
        union { __half2 h2[2]; float2 f2; } u;
        u.h2[0] = __floats2half2_rn(v.x, v.y);
        u.h2[1] = __floats2half2_rn(v.z, v.w);
        *(float2*)(xh + (size_t)g * 4) = u.f2;
        return;
    }
    g -= J_CVT;
    if (g < J_W) {
        if (g < 32768) {
            int n = g / IN_DIM, k = g - n * IN_DIM;
            Wt0[g] = __float2half(W0[(size_t)k * HC + n]);
        } else if (g < 98304) {
            int i = g - 32768;
            int n = i / HC, k = i - n * HC;
            Wt1[i] = __float2half(W1[(size_t)k * HC + n]);
        } else {
            int i = g - 98304;
            int n = i / HC, k = i - n * HC;
            Wt2[i] = __float2half(W2[(size_t)k * OUTD + n]);
        }
        return;
    }
    g -= J_W;
    if (g < N_NODES) { S2[g] = 0.f; return; }
    g -= N_NODES;
    if (g < N_NODES) D2[g] = 0.f;
}

// ---------------- fused CSR build: lookback scan + fill in ONE dispatch ------
// Blocks 0..97 scan counts -> offs (+ cursor via device atomics); block sums
// published with a +1 sentinel (bsums pre-zeroed). All blocks then spin on
// scan_done (device-scope atomic read) and fill csr via atomicAdd(cursor[dv]).
// All cross-block handoff (bsums, cursor, scan_done) uses device-scope atomics
// + __threadfence, so XCD-private L2s never serve stale data. offs/csr are
// plain stores consumed only by LATER dispatches.

__global__ void csr_k(const int* __restrict__ ei, const int* __restrict__ counts,
                      int* __restrict__ offs, int* __restrict__ cursor,
                      int* __restrict__ bsums, int* __restrict__ scan_done,
                      unsigned short* __restrict__ csr) {
    __shared__ int sm[512];
    __shared__ int base_sm;
    const int tid = threadIdx.x;

    if ((int)blockIdx.x < NB_SCAN) {
        int i = blockIdx.x * 512 + tid;
        int v = (i < N_NODES) ? counts[i] : 0;
        sm[tid] = v;
        __syncthreads();
        #pragma unroll
        for (int o = 1; o < 512; o <<= 1) {
            int add = (tid >= o) ? sm[tid - o] : 0;
            __syncthreads();
            sm[tid] += add;
            __syncthreads();
        }
        if (tid == 511) atomicExch(&bsums[blockIdx.x], sm[511] + 1);  // sentinel
        if (tid < 64) {
            int p = 0;
            for (int j = tid; j < (int)blockIdx.x; j += 64) {
                int v2;
                do { v2 = atomicAdd(&bsums[j], 0); } while (v2 == 0);
                p += v2 - 1;
            }
            #pragma unroll
            for (int o = 1; o < 64; o <<= 1) p += __shfl_xor(p, o, 64);
            if (tid == 0) base_sm = p;
        }
        __syncthreads();
        if (i < N_NODES) {
            int off = base_sm + sm[tid] - v;       // exclusive prefix
            offs[i] = off;
            atomicExch(&cursor[i], off);           // device-visible for fill
        }
        if (i == 0) offs[N_NODES] = ET;
        __threadfence();
        __syncthreads();
        if (tid == 0) atomicAdd(scan_done, 1);
    }

    // ---- fill phase (all blocks) ----
    if (tid == 0) {
        while (atomicAdd(scan_done, 0) < NB_SCAN) __builtin_amdgcn_s_sleep(8);
    }
    __syncthreads();
    __threadfence();
    int i = blockIdx.x * 512 + tid;
    if (i < ET) {
        int sv, dv;
        if (i < N_EDGES) { sv = ei[i]; dv = ei[N_EDGES + i]; }
        else             { sv = dv = i - N_EDGES; }
        int pos = atomicAdd(&cursor[dv], 1);
        csr[pos] = (unsigned short)sv;    // src < 50000 < 65536
    }
}

// ------- MFMA fp16 GEMM + fused attention scores (transposed accumulator) ----
// Round-3 proven structure: A and B staged via coalesced global_load_lds,
// single-buffered (inter-block overlap at ~4 blocks/CU hides the drain).
// Only change: C stored DIRECTLY from registers (uint2 per (i,j)) -- no LDS
// repack, no epilogue barriers, LDS = 32KB.

__device__ __forceinline__ void async_copy16(void* lds_base, const void* gaddr) {
    __builtin_amdgcn_global_load_lds(
        (const __attribute__((address_space(1))) unsigned int*)gaddr,
        (__attribute__((address_space(3))) unsigned int*)lds_base,
        16, 0, 0);
}

template<int H, int CD, bool ATOMIC>
__global__ __launch_bounds__(256) void gemm_mfma_k(const __half* __restrict__ A,
                                                   const __half* __restrict__ Wt,
                                                   __half* __restrict__ C,
                                                   const float* __restrict__ asrc,
                                                   const float* __restrict__ adst,
                                                   float* __restrict__ S,
                                                   float* __restrict__ D,
                                                   int M, int K, int N) {
    __shared__ __attribute__((aligned(16))) __half smem[2 * 128 * 64]; // 32KB
    __half* Ah = smem;
    __half* Bh = smem + 128 * 64;
    const int t = threadIdx.x;
    const int w = t >> 6;
    const int lane = t & 63;
    const int wm = w >> 1, wn = w & 1;
    const int cc = lane & 15;        // C-row within 16-block
    const int quad = lane >> 4;      // C-col quad
    const int row0 = blockIdx.x * 128;
    const int col0 = blockIdx.y * 128;

    f32x4 acc[4][4];
    #pragma unroll
    for (int i = 0; i < 4; ++i)
        #pragma unroll
        for (int j = 0; j < 4; ++j) acc[i][j] = (f32x4){0.f, 0.f, 0.f, 0.f};

    const int srow = lane >> 3;
    const int skq  = (lane & 7) * 8;

    for (int k0 = 0; k0 < K; k0 += 64) {
        __syncthreads();
        #pragma unroll
        for (int hh = 0; hh < 4; ++hh) {
            int ra = row0 + w * 32 + hh * 8 + srow;
            if (ra > M - 1) ra = M - 1;                    // clamp (discarded)
            async_copy16(&Ah[(w * 32 + hh * 8) * 64],
                         A + (size_t)ra * K + k0 + skq);
            int rb = col0 + w * 32 + hh * 8 + srow;        // N multiple of 128
            async_copy16(&Bh[(w * 32 + hh * 8) * 64],
                         Wt + (size_t)rb * K + k0 + skq);
        }
        __syncthreads();
        #pragma unroll
        for (int c = 0; c < 2; ++c) {
            half8 a[4], b[4];
            #pragma unroll
            for (int i = 0; i < 4; ++i)
                a[i] = *(const half8*)&Ah[(wm * 64 + i * 16 + cc) * 64 + c * 32 + quad * 8];
            #pragma unroll
            for (int j = 0; j < 4; ++j)
                b[j] = *(const half8*)&Bh[(wn * 64 + j * 16 + cc) * 64 + c * 32 + quad * 8];
            #pragma unroll
            for (int i = 0; i < 4; ++i)
                #pragma unroll
                for (int j = 0; j < 4; ++j)
                    acc[i][j] = __builtin_amdgcn_mfma_f32_16x16x32_f16(b[j], a[i], acc[i][j], 0, 0, 0);
        }
    }

    // ---- fused scores (registers + shfl only) ----
    const int hh_ = ATOMIC ? 0 : (blockIdx.y * 2 + wn);
    float4 asj[4], adj[4];
    #pragma unroll
    for (int j = 0; j < 4; ++j) {
        int cb = (ATOMIC ? wn * 64 : 0) + j * 16 + quad * 4;
        asj[j] = *(const float4*)&asrc[hh_ * CD + cb];
        adj[j] = *(const float4*)&adst[hh_ * CD + cb];
    }
    #pragma unroll
    for (int i = 0; i < 4; ++i) {
        float sv = 0.f, dv = 0.f;
        #pragma unroll
        for (int j = 0; j < 4; ++j) {
            sv = fmaf(acc[i][j][0], asj[j].x, sv); dv = fmaf(acc[i][j][0], adj[j].x, dv);
            sv = fmaf(acc[i][j][1], asj[j].y, sv); dv = fmaf(acc[i][j][1], adj[j].y, dv);
            sv = fmaf(acc[i][j][2], asj[j].z, sv); dv = fmaf(acc[i][j][2], adj[j].z, dv);
            sv = fmaf(acc[i][j][3], asj[j].w, sv); dv = fmaf(acc[i][j][3], adj[j].w, dv);
        }
        sv += __shfl_xor(sv, 16, 64); dv += __shfl_xor(dv, 16, 64);
        sv += __shfl_xor(sv, 32, 64); dv += __shfl_xor(dv, 32, 64);
        int r = row0 + wm * 64 + i * 16 + cc;
        if (quad == 0 && r < M) {
            if constexpr (ATOMIC) {
                atomicAdd(&S[r], sv);
                atomicAdd(&D[r], dv);
            } else {
                S[(size_t)r * H + hh_] = sv;
                D[(size_t)r * H + hh_] = dv;
            }
        }
    }

    // ---- C store direct from registers (8B per lane per (i,j)) ----
    #pragma unroll
    for (int i = 0; i < 4; ++i) {
        int gr = row0 + wm * 64 + i * 16 + cc;
        if (gr >= M) continue;
        #pragma unroll
        for (int j = 0; j < 4; ++j) {
            int tc = col0 + wn * 64 + j * 16 + quad * 4;
            union { __half2 h2[2]; uint2 u2; } pk;
            pk.h2[0] = __floats2half2_rn(acc[i][j][0], acc[i][j][1]);
            pk.h2[1] = __floats2half2_rn(acc[i][j][2], acc[i][j][3]);
            *(uint2*)&C[(size_t)gr * N + tc] = pk.u2;
        }
    }
}

// ---------------- per-dst-node aggregation (paired-edge, 32 lanes/edge) ------
// At the gather roofline (~3.7 TB/s on random 512B granules; FETCH = compulsory
// 8 XCD x 25.6 MB). Three structurally different variants all measured
// 63.5-64.1 us -> systemic ceiling, do not touch.

template<int H, int C, bool ELU_OUT, typename OT>
__global__ __launch_bounds__(256) void aggr_k(const __half* __restrict__ xp,
                                              const float* __restrict__ s,
                                              const float* __restrict__ d,
                                              const int* __restrict__ offs,
                                              const unsigned short* __restrict__ csr,
                                              const float* __restrict__ bias,
                                              OT* __restrict__ out) {
    constexpr int HCl = H * C;
    constexpr int FPL = HCl / 32;     // halfs per lane (8 or 4)
    constexpr int U = 8;              // edges per batch (4 per parity half)
    const int tid = threadIdx.x;
    const int lane = tid & 63;
    const int l = lane & 31;          // feature-lane within half
    const int par = lane >> 5;        // edge parity of this half
    int wid = blockIdx.x * 4 + (tid >> 6);
    if (wid >= N_NODES) return;
    const int h = (l * FPL) / C;      // head of this lane (0 when H==1)
    const int loff = l * FPL;         // halfs offset within row

    float dh = d[wid * H + h];
    float z = 0.f;
    float acc[FPL];
    #pragma unroll
    for (int k = 0; k < FPL; ++k) acc[k] = 0.f;

    const int e0 = offs[wid];
    const int e1 = offs[wid + 1];

    for (int j = e0; j < e1; j += U) {
        int ss[4];
        #pragma unroll
        for (int k2 = 0; k2 < 4; ++k2) {
            int idx = j + 2 * k2 + par;
            ss[k2] = csr[idx < e1 ? idx : e1 - 1];
        }
        float ev[4];
        #pragma unroll
        for (int k2 = 0; k2 < 4; ++k2)
            ev[k2] = s[ss[k2] * H + h];
        uint4 r4[4];
        uint2 r2[4];
        #pragma unroll
        for (int k2 = 0; k2 < 4; ++k2) {
            const __half* rowp = xp + (size_t)ss[k2] * HCl + loff;
            if constexpr (FPL == 8) r4[k2] = *(const uint4*)rowp;
            else                    r2[k2] = *(const uint2*)rowp;
        }
        #pragma unroll
        for (int k2 = 0; k2 < 4; ++k2) {
            float e = (j + 2 * k2 + par < e1) ? (ev[k2] + dh) : -1e30f;
            e = fmaxf(e, 0.2f * e);          // leaky_relu
            float pw = __expf(e);            // 0 for masked slots
            z += pw;
            if constexpr (FPL == 8) {
                union { uint4 u; __half2 h2[4]; } rr; rr.u = r4[k2];
                #pragma unroll
                for (int q = 0; q < 4; ++q) {
                    acc[2*q]   = fmaf(pw, __half2float(__low2half(rr.h2[q])),  acc[2*q]);
                    acc[2*q+1] = fmaf(pw, __half2float(__high2half(rr.h2[q])), acc[2*q+1]);
                }
            } else {
                union { uint2 u; __half2 h2[2]; } rr; rr.u = r2[k2];
                #pragma unroll
                for (int q = 0; q < 2; ++q) {
                    acc[2*q]   = fmaf(pw, __half2float(__low2half(rr.h2[q])),  acc[2*q]);
                    acc[2*q+1] = fmaf(pw, __half2float(__high2half(rr.h2[q])), acc[2*q+1]);
                }
            }
        }
    }

    // merge the two parity halves (lane l and l+32 hold the same features)
    z += __shfl_xor(z, 32, 64);
    #pragma unroll
    for (int k = 0; k < FPL; ++k) acc[k] += __shfl_xor(acc[k], 32, 64);

    if (lane >= 32) return;   // lower half writes

    float inv = 1.f / (z + 1e-16f);
    float o[FPL];
    #pragma unroll
    for (int k = 0; k < FPL; ++k) {
        o[k] = acc[k] * inv + bias[loff + k];
        if constexpr (ELU_OUT) o[k] = (o[k] > 0.f) ? o[k] : (__expf(o[k]) - 1.f);
    }
    if constexpr (sizeof(OT) == 2 && FPL == 8) {
        union { __half2 h2[4]; uint4 u4; } u;
        u.h2[0] = __floats2half2_rn(o[0], o[1]);
        u.h2[1] = __floats2half2_rn(o[2], o[3]);
        u.h2[2] = __floats2half2_rn(o[4], o[5]);
        u.h2[3] = __floats2half2_rn(o[6], o[7]);
        *(uint4*)((__half*)out + (size_t)wid * HCl + loff) = u.u4;
    } else if constexpr (sizeof(OT) == 4 && FPL == 4) {
        float4 v; v.x = o[0]; v.y = o[1]; v.z = o[2]; v.w = o[3];
        *(float4*)((float*)out + (size_t)wid * HCl + loff) = v;
    } else {
        #pragma unroll
        for (int k = 0; k < FPL; ++k)
            out[(size_t)wid * HCl + loff + k] = (OT)o[k];
    }
}

// ---------------- launch ----------------

extern "C" void kernel_launch(void* const* d_in, const int* in_sizes, int n_in,
                              void* d_out, int out_size, void* d_ws, size_t ws_size,
                              hipStream_t stream) {
    const float* x      = (const float*)d_in[0];
    const int*   ei     = (const int*)  d_in[1];
    const float* W0     = (const float*)d_in[2];
    const float* as0    = (const float*)d_in[3];
    const float* ad0    = (const float*)d_in[4];
    const float* b0     = (const float*)d_in[5];
    const float* W1     = (const float*)d_in[6];
    const float* as1    = (const float*)d_in[7];
    const float* ad1    = (const float*)d_in[8];
    const float* b1     = (const float*)d_in[9];
    const float* W2     = (const float*)d_in[10];
    const float* as2    = (const float*)d_in[11];
    const float* ad2    = (const float*)d_in[12];
    const float* b2     = (const float*)d_in[13];
    float* out = (float*)d_out;

    // workspace layout (256B aligned chunks)
    char* p = (char*)d_ws;
    auto take = [&](size_t bytes) {
        char* r = p;
        p += (bytes + 255) & ~(size_t)255;
        return r;
    };
    __half* XPh   = (__half*)take((size_t)N_NODES * HC * 2);
    __half* Hbuf  = (__half*)take((size_t)N_NODES * HC * 2);
    __half* xh    = (__half*)take((size_t)N_NODES * IN_DIM * 2);
    __half* Wt0   = (__half*)take((size_t)IN_DIM * HC * 2);
    __half* Wt1   = (__half*)take((size_t)HC * HC * 2);
    __half* Wt2   = (__half*)take((size_t)HC * OUTD * 2);
    float*  S     = (float*) take((size_t)N_NODES * HEADS * 4);
    float*  D     = (float*) take((size_t)N_NODES * HEADS * 4);
    float*  S2    = (float*) take((size_t)N_NODES * 4);
    float*  D2    = (float*) take((size_t)N_NODES * 4);
    // zero-blob: counts | bsums(128) | scan_done  (single memset)
    int*    zblob = (int*)   take((size_t)(N_NODES + 128 + 16) * 4);
    int*    counts    = zblob;
    int*    bsums     = zblob + N_NODES;
    int*    scan_done = zblob + N_NODES + 128;
    int*    offs  = (int*)   take((size_t)(N_NODES + 1) * 4);
    int*    cursor= (int*)   take((size_t)N_NODES * 4);
    unsigned short* csr = (unsigned short*)take((size_t)ET * 2);

    const int ET_BLOCKS512 = (ET + 511) / 512;   // 1661
    const int NODE_BLOCKS = (N_NODES + 3) / 4;   // 12500
    const int MB = (N_NODES + 127) / 128;        // 391
    dim3 g0(MB, HC / 128);                       // 391 x 2
    dim3 g2(MB, OUTD / 128);                     // 391 x 1

    // ---- setup: zero blob; fused hist + cvt + wtrans + zero S2/D2 ----
    hipMemsetAsync(zblob, 0, (size_t)(N_NODES + 128 + 16) * 4, stream);
    setup_k<<<(SETUP_TOTAL + 255) / 256, 256, 0, stream>>>(
        ei, counts, x, xh, W0, Wt0, W1, Wt1, W2, Wt2, S2, D2);

    // ---- fused CSR build (scan + fill, one dispatch) ----
    csr_k<<<ET_BLOCKS512, 512, 0, stream>>>(ei, counts, offs, cursor, bsums, scan_done, csr);

    // ---- layer 0: 128 -> 4x64, concat, ELU ----
    gemm_mfma_k<HEADS, HID, false><<<g0, 256, 0, stream>>>(xh, Wt0, XPh, as0, ad0, S, D, N_NODES, IN_DIM, HC);
    aggr_k<HEADS, HID, true, __half><<<NODE_BLOCKS, 256, 0, stream>>>(XPh, S, D, offs, csr, b0, Hbuf);

    // ---- layer 1: 256 -> 4x64, concat, ELU ----
    gemm_mfma_k<HEADS, HID, false><<<g0, 256, 0, stream>>>(Hbuf, Wt1, XPh, as1, ad1, S, D, N_NODES, HC, HC);
    aggr_k<HEADS, HID, true, __half><<<NODE_BLOCKS, 256, 0, stream>>>(XPh, S, D, offs, csr, b1, Hbuf);

    // ---- layer 2: 256 -> 1x128, mean(H=1), no ELU ----
    gemm_mfma_k<1, OUTD, true><<<g2, 256, 0, stream>>>(Hbuf, Wt2, XPh, as2, ad2, S2, D2, N_NODES, HC, OUTD);
    aggr_k<1, OUTD, false, float><<<NODE_BLOCKS, 256, 0, stream>>>(XPh, S2, D2, offs, csr, b2, out);
}

// Round 6
// 396.232 us; speedup vs baseline: 1.6242x; 1.6242x over previous
//
#include <hip/hip_runtime.h>
#include <hip/hip_bf16.h>
#include <hip/hip_fp16.h>
#include <math.h>

#define N_NODES 50000
#define N_EDGES 800000
#define ET      (N_EDGES + N_NODES)   // with self loops
#define IN_DIM  128
#define HEADS   4
#define HID     64
#define HC      256                   // HEADS*HID
#define OUTD    128

typedef _Float16 half8 __attribute__((ext_vector_type(8)));
typedef float f32x4 __attribute__((ext_vector_type(4)));

// ---------------- CSR build (three proven dispatches) ----------------

__global__ void scan1_k(const int* __restrict__ counts, int* __restrict__ offs,
                        int* __restrict__ bsums) {
    __shared__ int sm[512];
    int tid = threadIdx.x;
    int i = blockIdx.x * 512 + tid;
    int v = (i < N_NODES) ? counts[i] : 0;
    sm[tid] = v;
    __syncthreads();
    #pragma unroll
    for (int o = 1; o < 512; o <<= 1) {
        int add = (tid >= o) ? sm[tid - o] : 0;
        __syncthreads();
        sm[tid] += add;
        __syncthreads();
    }
    if (i < N_NODES) offs[i] = sm[tid] - v;        // exclusive within block
    if (tid == 511) bsums[blockIdx.x] = sm[511];
}

// adds prefix of bsums; each block computes its own prefix redundantly
__global__ void scan3_k(int* __restrict__ offs, const int* __restrict__ bsums) {
    __shared__ int base_sm;
    int tid = threadIdx.x;
    if (tid < 64) {
        int p = 0;
        for (int j = tid; j < (int)blockIdx.x; j += 64) p += bsums[j];
        #pragma unroll
        for (int o = 1; o < 64; o <<= 1) p += __shfl_xor(p, o, 64);
        if (tid == 0) base_sm = p;
    }
    __syncthreads();
    int i = blockIdx.x * 512 + tid;
    if (i < N_NODES) offs[i] += base_sm;
    if (i == 0) offs[N_NODES] = ET;
}

// fill using counts as a countdown cursor (counts holds degree post-hist)
__global__ void fill_k(const int* __restrict__ ei, const int* __restrict__ offs,
                       int* __restrict__ counts, unsigned short* __restrict__ csr) {
    int i = blockIdx.x * blockDim.x + threadIdx.x;
    if (i >= ET) return;
    int sv, dv;
    if (i < N_EDGES) { sv = ei[i]; dv = ei[N_EDGES + i]; }
    else             { sv = dv = i - N_EDGES; }
    int pos = offs[dv] + atomicSub(&counts[dv], 1) - 1;
    csr[pos] = (unsigned short)sv;    // src < 50000 < 65536
}

// ---------------- fused setup: hist + x->fp16 + W transposes + zero S2/D2 ----

#define J_HIST  ET                       // 850000
#define J_CVT   (N_NODES * IN_DIM / 4)   // 1600000
#define J_W     131072
#define SETUP_TOTAL (J_HIST + J_CVT + J_W + 2 * N_NODES)

__global__ void setup_k(const int* __restrict__ ei, int* __restrict__ counts,
                        const float* __restrict__ x, __half* __restrict__ xh,
                        const float* __restrict__ W0, __half* __restrict__ Wt0,
                        const float* __restrict__ W1, __half* __restrict__ Wt1,
                        const float* __restrict__ W2, __half* __restrict__ Wt2,
                        float* __restrict__ S2, float* __restrict__ D2) {
    int g = blockIdx.x * 256 + threadIdx.x;
    if (g < J_HIST) {
        int dv = (g < N_EDGES) ? ei[N_EDGES + g] : (g - N_EDGES);
        atomicAdd(&counts[dv], 1);
        return;
    }
    g -= J_HIST;
    if (g < J_CVT) {
        float4 v = *(const float4*)(x + (size_t)g * 4);
        union { __half2 h2[2]; float2 f2; } u;
        u.h2[0] = __floats2half2_rn(v.x, v.y);
        u.h2[1] = __floats2half2_rn(v.z, v.w);
        *(float2*)(xh + (size_t)g * 4) = u.f2;
        return;
    }
    g -= J_CVT;
    if (g < J_W) {
        if (g < 32768) {
            int n = g / IN_DIM, k = g - n * IN_DIM;
            Wt0[g] = __float2half(W0[(size_t)k * HC + n]);
        } else if (g < 98304) {
            int i = g - 32768;
            int n = i / HC, k = i - n * HC;
            Wt1[i] = __float2half(W1[(size_t)k * HC + n]);
        } else {
            int i = g - 98304;
            int n = i / HC, k = i - n * HC;
            Wt2[i] = __float2half(W2[(size_t)k * OUTD + n]);
        }
        return;
    }
    g -= J_W;
    if (g < N_NODES) { S2[g] = 0.f; return; }
    g -= N_NODES;
    if (g < N_NODES) D2[g] = 0.f;
}

// ------- MFMA fp16 GEMM + fused attention scores (transposed accumulator) ----
// r3 staging structure (A and B via coalesced global_load_lds, single-buffered;
// inter-block overlap at ~4 blocks/CU hides the per-chunk drain) + r5's direct
// register C-store epilogue (no LDS repack, no epilogue barriers; measured
// ~25us total saving across the three GEMMs).

__device__ __forceinline__ void async_copy16(void* lds_base, const void* gaddr) {
    __builtin_amdgcn_global_load_lds(
        (const __attribute__((address_space(1))) unsigned int*)gaddr,
        (__attribute__((address_space(3))) unsigned int*)lds_base,
        16, 0, 0);
}

template<int H, int CD, bool ATOMIC>
__global__ __launch_bounds__(256) void gemm_mfma_k(const __half* __restrict__ A,
                                                   const __half* __restrict__ Wt,
                                                   __half* __restrict__ C,
                                                   const float* __restrict__ asrc,
                                                   const float* __restrict__ adst,
                                                   float* __restrict__ S,
                                                   float* __restrict__ D,
                                                   int M, int K, int N) {
    __shared__ __attribute__((aligned(16))) __half smem[2 * 128 * 64]; // 32KB
    __half* Ah = smem;
    __half* Bh = smem + 128 * 64;
    const int t = threadIdx.x;
    const int w = t >> 6;
    const int lane = t & 63;
    const int wm = w >> 1, wn = w & 1;
    const int cc = lane & 15;        // C-row within 16-block
    const int quad = lane >> 4;      // C-col quad
    const int row0 = blockIdx.x * 128;
    const int col0 = blockIdx.y * 128;

    f32x4 acc[4][4];
    #pragma unroll
    for (int i = 0; i < 4; ++i)
        #pragma unroll
        for (int j = 0; j < 4; ++j) acc[i][j] = (f32x4){0.f, 0.f, 0.f, 0.f};

    const int srow = lane >> 3;
    const int skq  = (lane & 7) * 8;

    for (int k0 = 0; k0 < K; k0 += 64) {
        __syncthreads();
        #pragma unroll
        for (int hh = 0; hh < 4; ++hh) {
            int ra = row0 + w * 32 + hh * 8 + srow;
            if (ra > M - 1) ra = M - 1;                    // clamp (discarded)
            async_copy16(&Ah[(w * 32 + hh * 8) * 64],
                         A + (size_t)ra * K + k0 + skq);
            int rb = col0 + w * 32 + hh * 8 + srow;        // N multiple of 128
            async_copy16(&Bh[(w * 32 + hh * 8) * 64],
                         Wt + (size_t)rb * K + k0 + skq);
        }
        __syncthreads();
        #pragma unroll
        for (int c = 0; c < 2; ++c) {
            half8 a[4], b[4];
            #pragma unroll
            for (int i = 0; i < 4; ++i)
                a[i] = *(const half8*)&Ah[(wm * 64 + i * 16 + cc) * 64 + c * 32 + quad * 8];
            #pragma unroll
            for (int j = 0; j < 4; ++j)
                b[j] = *(const half8*)&Bh[(wn * 64 + j * 16 + cc) * 64 + c * 32 + quad * 8];
            #pragma unroll
            for (int i = 0; i < 4; ++i)
                #pragma unroll
                for (int j = 0; j < 4; ++j)
                    acc[i][j] = __builtin_amdgcn_mfma_f32_16x16x32_f16(b[j], a[i], acc[i][j], 0, 0, 0);
        }
    }

    // ---- fused scores (registers + shfl only) ----
    const int hh_ = ATOMIC ? 0 : (blockIdx.y * 2 + wn);
    float4 asj[4], adj[4];
    #pragma unroll
    for (int j = 0; j < 4; ++j) {
        int cb = (ATOMIC ? wn * 64 : 0) + j * 16 + quad * 4;
        asj[j] = *(const float4*)&asrc[hh_ * CD + cb];
        adj[j] = *(const float4*)&adst[hh_ * CD + cb];
    }
    #pragma unroll
    for (int i = 0; i < 4; ++i) {
        float sv = 0.f, dv = 0.f;
        #pragma unroll
        for (int j = 0; j < 4; ++j) {
            sv = fmaf(acc[i][j][0], asj[j].x, sv); dv = fmaf(acc[i][j][0], adj[j].x, dv);
            sv = fmaf(acc[i][j][1], asj[j].y, sv); dv = fmaf(acc[i][j][1], adj[j].y, dv);
            sv = fmaf(acc[i][j][2], asj[j].z, sv); dv = fmaf(acc[i][j][2], adj[j].z, dv);
            sv = fmaf(acc[i][j][3], asj[j].w, sv); dv = fmaf(acc[i][j][3], adj[j].w, dv);
        }
        sv += __shfl_xor(sv, 16, 64); dv += __shfl_xor(dv, 16, 64);
        sv += __shfl_xor(sv, 32, 64); dv += __shfl_xor(dv, 32, 64);
        int r = row0 + wm * 64 + i * 16 + cc;
        if (quad == 0 && r < M) {
            if constexpr (ATOMIC) {
                atomicAdd(&S[r], sv);
                atomicAdd(&D[r], dv);
            } else {
                S[(size_t)r * H + hh_] = sv;
                D[(size_t)r * H + hh_] = dv;
            }
        }
    }

    // ---- C store direct from registers (8B per lane per (i,j)) ----
    #pragma unroll
    for (int i = 0; i < 4; ++i) {
        int gr = row0 + wm * 64 + i * 16 + cc;
        if (gr >= M) continue;
        #pragma unroll
        for (int j = 0; j < 4; ++j) {
            int tc = col0 + wn * 64 + j * 16 + quad * 4;
            union { __half2 h2[2]; uint2 u2; } pk;
            pk.h2[0] = __floats2half2_rn(acc[i][j][0], acc[i][j][1]);
            pk.h2[1] = __floats2half2_rn(acc[i][j][2], acc[i][j][3]);
            *(uint2*)&C[(size_t)gr * N + tc] = pk.u2;
        }
    }
}

// ---------------- per-dst-node aggregation (paired-edge, 32 lanes/edge) ------
// At the gather roofline (~3.7 TB/s on random 512B granules; FETCH = compulsory
// 8 XCD x 25.6 MB). Three structurally different variants all measured
// 63.5-64.1 us -> systemic ceiling, do not touch.

template<int H, int C, bool ELU_OUT, typename OT>
__global__ __launch_bounds__(256) void aggr_k(const __half* __restrict__ xp,
                                              const float* __restrict__ s,
                                              const float* __restrict__ d,
                                              const int* __restrict__ offs,
                                              const unsigned short* __restrict__ csr,
                                              const float* __restrict__ bias,
                                              OT* __restrict__ out) {
    constexpr int HCl = H * C;
    constexpr int FPL = HCl / 32;     // halfs per lane (8 or 4)
    constexpr int U = 8;              // edges per batch (4 per parity half)
    const int tid = threadIdx.x;
    const int lane = tid & 63;
    const int l = lane & 31;          // feature-lane within half
    const int par = lane >> 5;        // edge parity of this half
    int wid = blockIdx.x * 4 + (tid >> 6);
    if (wid >= N_NODES) return;
    const int h = (l * FPL) / C;      // head of this lane (0 when H==1)
    const int loff = l * FPL;         // halfs offset within row

    float dh = d[wid * H + h];
    float z = 0.f;
    float acc[FPL];
    #pragma unroll
    for (int k = 0; k < FPL; ++k) acc[k] = 0.f;

    const int e0 = offs[wid];
    const int e1 = offs[wid + 1];

    for (int j = e0; j < e1; j += U) {
        int ss[4];
        #pragma unroll
        for (int k2 = 0; k2 < 4; ++k2) {
            int idx = j + 2 * k2 + par;
            ss[k2] = csr[idx < e1 ? idx : e1 - 1];
        }
        float ev[4];
        #pragma unroll
        for (int k2 = 0; k2 < 4; ++k2)
            ev[k2] = s[ss[k2] * H + h];
        uint4 r4[4];
        uint2 r2[4];
        #pragma unroll
        for (int k2 = 0; k2 < 4; ++k2) {
            const __half* rowp = xp + (size_t)ss[k2] * HCl + loff;
            if constexpr (FPL == 8) r4[k2] = *(const uint4*)rowp;
            else                    r2[k2] = *(const uint2*)rowp;
        }
        #pragma unroll
        for (int k2 = 0; k2 < 4; ++k2) {
            float e = (j + 2 * k2 + par < e1) ? (ev[k2] + dh) : -1e30f;
            e = fmaxf(e, 0.2f * e);          // leaky_relu
            float pw = __expf(e);            // 0 for masked slots
            z += pw;
            if constexpr (FPL == 8) {
                union { uint4 u; __half2 h2[4]; } rr; rr.u = r4[k2];
                #pragma unroll
                for (int q = 0; q < 4; ++q) {
                    acc[2*q]   = fmaf(pw, __half2float(__low2half(rr.h2[q])),  acc[2*q]);
                    acc[2*q+1] = fmaf(pw, __half2float(__high2half(rr.h2[q])), acc[2*q+1]);
                }
            } else {
                union { uint2 u; __half2 h2[2]; } rr; rr.u = r2[k2];
                #pragma unroll
                for (int q = 0; q < 2; ++q) {
                    acc[2*q]   = fmaf(pw, __half2float(__low2half(rr.h2[q])),  acc[2*q]);
                    acc[2*q+1] = fmaf(pw, __half2float(__high2half(rr.h2[q])), acc[2*q+1]);
                }
            }
        }
    }

    // merge the two parity halves (lane l and l+32 hold the same features)
    z += __shfl_xor(z, 32, 64);
    #pragma unroll
    for (int k = 0; k < FPL; ++k) acc[k] += __shfl_xor(acc[k], 32, 64);

    if (lane >= 32) return;   // lower half writes

    float inv = 1.f / (z + 1e-16f);
    float o[FPL];
    #pragma unroll
    for (int k = 0; k < FPL; ++k) {
        o[k] = acc[k] * inv + bias[loff + k];
        if constexpr (ELU_OUT) o[k] = (o[k] > 0.f) ? o[k] : (__expf(o[k]) - 1.f);
    }
    if constexpr (sizeof(OT) == 2 && FPL == 8) {
        union { __half2 h2[4]; uint4 u4; } u;
        u.h2[0] = __floats2half2_rn(o[0], o[1]);
        u.h2[1] = __floats2half2_rn(o[2], o[3]);
        u.h2[2] = __floats2half2_rn(o[4], o[5]);
        u.h2[3] = __floats2half2_rn(o[6], o[7]);
        *(uint4*)((__half*)out + (size_t)wid * HCl + loff) = u.u4;
    } else if constexpr (sizeof(OT) == 4 && FPL == 4) {
        float4 v; v.x = o[0]; v.y = o[1]; v.z = o[2]; v.w = o[3];
        *(float4*)((float*)out + (size_t)wid * HCl + loff) = v;
    } else {
        #pragma unroll
        for (int k = 0; k < FPL; ++k)
            out[(size_t)wid * HCl + loff + k] = (OT)o[k];
    }
}

// ---------------- launch ----------------

extern "C" void kernel_launch(void* const* d_in, const int* in_sizes, int n_in,
                              void* d_out, int out_size, void* d_ws, size_t ws_size,
                              hipStream_t stream) {
    const float* x      = (const float*)d_in[0];
    const int*   ei     = (const int*)  d_in[1];
    const float* W0     = (const float*)d_in[2];
    const float* as0    = (const float*)d_in[3];
    const float* ad0    = (const float*)d_in[4];
    const float* b0     = (const float*)d_in[5];
    const float* W1     = (const float*)d_in[6];
    const float* as1    = (const float*)d_in[7];
    const float* ad1    = (const float*)d_in[8];
    const float* b1     = (const float*)d_in[9];
    const float* W2     = (const float*)d_in[10];
    const float* as2    = (const float*)d_in[11];
    const float* ad2    = (const float*)d_in[12];
    const float* b2     = (const float*)d_in[13];
    float* out = (float*)d_out;

    // workspace layout (256B aligned chunks)
    char* p = (char*)d_ws;
    auto take = [&](size_t bytes) {
        char* r = p;
        p += (bytes + 255) & ~(size_t)255;
        return r;
    };
    __half* XPh   = (__half*)take((size_t)N_NODES * HC * 2);
    __half* Hbuf  = (__half*)take((size_t)N_NODES * HC * 2);
    __half* xh    = (__half*)take((size_t)N_NODES * IN_DIM * 2);
    __half* Wt0   = (__half*)take((size_t)IN_DIM * HC * 2);
    __half* Wt1   = (__half*)take((size_t)HC * HC * 2);
    __half* Wt2   = (__half*)take((size_t)HC * OUTD * 2);
    float*  S     = (float*) take((size_t)N_NODES * HEADS * 4);
    float*  D     = (float*) take((size_t)N_NODES * HEADS * 4);
    float*  S2    = (float*) take((size_t)N_NODES * 4);
    float*  D2    = (float*) take((size_t)N_NODES * 4);
    int*    counts= (int*)   take((size_t)N_NODES * 4);
    int*    offs  = (int*)   take((size_t)(N_NODES + 1) * 4);
    int*    bsums = (int*)   take(512 * 4);
    unsigned short* csr = (unsigned short*)take((size_t)ET * 2);

    const int NB_SCAN = (N_NODES + 511) / 512;   // 98
    const int ET_BLOCKS = (ET + 255) / 256;
    const int NODE_BLOCKS = (N_NODES + 3) / 4;   // 12500
    const int MB = (N_NODES + 127) / 128;        // 391
    dim3 g0(MB, HC / 128);                       // 391 x 2
    dim3 g2(MB, OUTD / 128);                     // 391 x 1

    // ---- setup: zero counts; fused hist + cvt + wtrans + zero S2/D2 ----
    hipMemsetAsync(counts, 0, (size_t)N_NODES * 4, stream);
    setup_k<<<(SETUP_TOTAL + 255) / 256, 256, 0, stream>>>(
        ei, counts, x, xh, W0, Wt0, W1, Wt1, W2, Wt2, S2, D2);

    // ---- CSR scan + fill ----
    scan1_k<<<NB_SCAN, 512, 0, stream>>>(counts, offs, bsums);
    scan3_k<<<NB_SCAN, 512, 0, stream>>>(offs, bsums);
    fill_k<<<ET_BLOCKS, 256, 0, stream>>>(ei, offs, counts, csr);

    // ---- layer 0: 128 -> 4x64, concat, ELU ----
    gemm_mfma_k<HEADS, HID, false><<<g0, 256, 0, stream>>>(xh, Wt0, XPh, as0, ad0, S, D, N_NODES, IN_DIM, HC);
    aggr_k<HEADS, HID, true, __half><<<NODE_BLOCKS, 256, 0, stream>>>(XPh, S, D, offs, csr, b0, Hbuf);

    // ---- layer 1: 256 -> 4x64, concat, ELU ----
    gemm_mfma_k<HEADS, HID, false><<<g0, 256, 0, stream>>>(Hbuf, Wt1, XPh, as1, ad1, S, D, N_NODES, HC, HC);
    aggr_k<HEADS, HID, true, __half><<<NODE_BLOCKS, 256, 0, stream>>>(XPh, S, D, offs, csr, b1, Hbuf);

    // ---- layer 2: 256 -> 1x128, mean(H=1), no ELU ----
    gemm_mfma_k<1, OUTD, true><<<g2, 256, 0, stream>>>(Hbuf, Wt2, XPh, as2, ad2, S2, D2, N_NODES, HC, OUTD);
    aggr_k<1, OUTD, false, float><<<NODE_BLOCKS, 256, 0, stream>>>(XPh, S2, D2, offs, csr, b2, out);
}

// Round 7
// 388.386 us; speedup vs baseline: 1.6570x; 1.0202x over previous
//
#include <hip/hip_runtime.h>
#include <hip/hip_bf16.h>
#include <hip/hip_fp16.h>
#include <math.h>

#define N_NODES 50000
#define N_EDGES 800000
#define ET      (N_EDGES + N_NODES)   // with self loops
#define IN_DIM  128
#define HEADS   4
#define HID     64
#define HC      256                   // HEADS*HID
#define OUTD    128

typedef _Float16 half8 __attribute__((ext_vector_type(8)));
typedef float f32x4 __attribute__((ext_vector_type(4)));

// ---------------- CSR build (three proven dispatches) ----------------

__global__ void scan1_k(const int* __restrict__ counts, int* __restrict__ offs,
                        int* __restrict__ bsums) {
    __shared__ int sm[512];
    int tid = threadIdx.x;
    int i = blockIdx.x * 512 + tid;
    int v = (i < N_NODES) ? counts[i] : 0;
    sm[tid] = v;
    __syncthreads();
    #pragma unroll
    for (int o = 1; o < 512; o <<= 1) {
        int add = (tid >= o) ? sm[tid - o] : 0;
        __syncthreads();
        sm[tid] += add;
        __syncthreads();
    }
    if (i < N_NODES) offs[i] = sm[tid] - v;        // exclusive within block
    if (tid == 511) bsums[blockIdx.x] = sm[511];
}

// adds prefix of bsums; each block computes its own prefix redundantly
__global__ void scan3_k(int* __restrict__ offs, const int* __restrict__ bsums) {
    __shared__ int base_sm;
    int tid = threadIdx.x;
    if (tid < 64) {
        int p = 0;
        for (int j = tid; j < (int)blockIdx.x; j += 64) p += bsums[j];
        #pragma unroll
        for (int o = 1; o < 64; o <<= 1) p += __shfl_xor(p, o, 64);
        if (tid == 0) base_sm = p;
    }
    __syncthreads();
    int i = blockIdx.x * 512 + tid;
    if (i < N_NODES) offs[i] += base_sm;
    if (i == 0) offs[N_NODES] = ET;
}

// fill using counts as a countdown cursor (counts holds degree post-hist)
__global__ void fill_k(const int* __restrict__ ei, const int* __restrict__ offs,
                       int* __restrict__ counts, unsigned short* __restrict__ csr) {
    int i = blockIdx.x * blockDim.x + threadIdx.x;
    if (i >= ET) return;
    int sv, dv;
    if (i < N_EDGES) { sv = ei[i]; dv = ei[N_EDGES + i]; }
    else             { sv = dv = i - N_EDGES; }
    int pos = offs[dv] + atomicSub(&counts[dv], 1) - 1;
    csr[pos] = (unsigned short)sv;    // src < 50000 < 65536
}

// ---------------- fused setup: hist + x->fp16 + W transposes + zero S2/D2 ----

#define J_HIST  ET                       // 850000
#define J_CVT   (N_NODES * IN_DIM / 4)   // 1600000
#define J_W     131072
#define SETUP_TOTAL (J_HIST + J_CVT + J_W + 2 * N_NODES)

__global__ void setup_k(const int* __restrict__ ei, int* __restrict__ counts,
                        const float* __restrict__ x, __half* __restrict__ xh,
                        const float* __restrict__ W0, __half* __restrict__ Wt0,
                        const float* __restrict__ W1, __half* __restrict__ Wt1,
                        const float* __restrict__ W2, __half* __restrict__ Wt2,
                        float* __restrict__ S2, float* __restrict__ D2) {
    int g = blockIdx.x * 256 + threadIdx.x;
    if (g < J_HIST) {
        int dv = (g < N_EDGES) ? ei[N_EDGES + g] : (g - N_EDGES);
        atomicAdd(&counts[dv], 1);
        return;
    }
    g -= J_HIST;
    if (g < J_CVT) {
        float4 v = *(const float4*)(x + (size_t)g * 4);
        union { __half2 h2[2]; float2 f2; } u;
        u.h2[0] = __floats2half2_rn(v.x, v.y);
        u.h2[1] = __floats2half2_rn(v.z, v.w);
        *(float2*)(xh + (size_t)g * 4) = u.f2;
        return;
    }
    g -= J_CVT;
    if (g < J_W) {
        if (g < 32768) {
            int n = g / IN_DIM, k = g - n * IN_DIM;
            Wt0[g] = __float2half(W0[(size_t)k * HC + n]);
        } else if (g < 98304) {
            int i = g - 32768;
            int n = i / HC, k = i - n * HC;
            Wt1[i] = __float2half(W1[(size_t)k * HC + n]);
        } else {
            int i = g - 98304;
            int n = i / HC, k = i - n * HC;
            Wt2[i] = __float2half(W2[(size_t)k * OUTD + n]);
        }
        return;
    }
    g -= J_W;
    if (g < N_NODES) { S2[g] = 0.f; return; }
    g -= N_NODES;
    if (g < N_NODES) D2[g] = 0.f;
}

// ------- MFMA fp16 GEMM + fused attention scores (transposed accumulator) ----
// v7: T3-style pipelined K-loop. BK=32, TRIPLE-buffered LDS (3 x 16KB), depth-2
// prefetch: at chunk t issue stage(t+2); compute chunk t; then counted
// s_waitcnt vmcnt(4) (= stage(t+1) landed; 4 gload_lds per thread per stage,
// in-order retirement) + raw s_barrier + sched_barrier(0). ONE barrier per
// chunk, loads stay in flight across barriers (never vmcnt(0) mid-loop).
// K is a template parameter so the loop fully unrolls and vmcnt is a literal.
// Fragment math / fused scores / direct-register C store unchanged from r6.

__device__ __forceinline__ void async_copy16(void* lds_base, const void* gaddr) {
    __builtin_amdgcn_global_load_lds(
        (const __attribute__((address_space(1))) unsigned int*)gaddr,
        (__attribute__((address_space(3))) unsigned int*)lds_base,
        16, 0, 0);
}

template<int H, int CD, bool ATOMIC, int K>
__global__ __launch_bounds__(256) void gemm_mfma_k(const __half* __restrict__ A,
                                                   const __half* __restrict__ Wt,
                                                   __half* __restrict__ C,
                                                   const float* __restrict__ asrc,
                                                   const float* __restrict__ adst,
                                                   float* __restrict__ S,
                                                   float* __restrict__ D,
                                                   int M, int N) {
    constexpr int KC = K / 32;                 // 4 (K=128) or 8 (K=256)
    // [buf][ A: 128 rows x 32 halfs | B: 128 rows x 32 halfs ] = 16KB per buf
    __shared__ __attribute__((aligned(16))) __half smem[3][8192];  // 48KB
    const int t = threadIdx.x;
    const int w = t >> 6;
    const int lane = t & 63;
    const int wm = w >> 1, wn = w & 1;
    const int cc = lane & 15;        // C-row within 16-block
    const int quad = lane >> 4;      // C-col quad
    const int row0 = blockIdx.x * 128;
    const int col0 = blockIdx.y * 128;
    const int srow = lane >> 2;      // 0..15: row within 16-row group
    const int skq  = (lane & 3) * 8; // halfs: 16B slot within 64B row

    auto stage = [&](int kc, int b) {
        #pragma unroll
        for (int g = 0; g < 2; ++g) {
            int rgrp = w * 32 + g * 16;                // wave-uniform row group
            int ra = row0 + rgrp + srow;
            if (ra > M - 1) ra = M - 1;                // clamp (discarded)
            async_copy16(&smem[b][rgrp * 32],
                         A + (size_t)ra * K + kc * 32 + skq);
            int rb = col0 + rgrp + srow;               // N multiple of 128
            async_copy16(&smem[b][4096 + rgrp * 32],
                         Wt + (size_t)rb * K + kc * 32 + skq);
        }
    };

    f32x4 acc[4][4];
    #pragma unroll
    for (int i = 0; i < 4; ++i)
        #pragma unroll
        for (int j = 0; j < 4; ++j) acc[i][j] = (f32x4){0.f, 0.f, 0.f, 0.f};

    // prologue: two stages in flight, wait for the first only
    stage(0, 0);
    stage(1, 1);
    asm volatile("s_waitcnt vmcnt(4)" ::: "memory");   // stage(0) landed
    __builtin_amdgcn_s_barrier();
    __builtin_amdgcn_sched_barrier(0);

    #pragma unroll
    for (int kc = 0; kc < KC; ++kc) {
        if (kc + 2 < KC) stage(kc + 2, (kc + 2) % 3);

        const __half* Ab = smem[kc % 3];
        half8 a[4], b[4];
        #pragma unroll
        for (int i = 0; i < 4; ++i)
            a[i] = *(const half8*)&Ab[(wm * 64 + i * 16 + cc) * 32 + quad * 8];
        #pragma unroll
        for (int j = 0; j < 4; ++j)
            b[j] = *(const half8*)&Ab[4096 + (wn * 64 + j * 16 + cc) * 32 + quad * 8];
        #pragma unroll
        for (int i = 0; i < 4; ++i)
            #pragma unroll
            for (int j = 0; j < 4; ++j)
                acc[i][j] = __builtin_amdgcn_mfma_f32_16x16x32_f16(b[j], a[i], acc[i][j], 0, 0, 0);

        if (kc + 1 < KC) {
            if (kc + 2 < KC)
                asm volatile("s_waitcnt vmcnt(4)" ::: "memory");  // stage(kc+1) landed
            else
                asm volatile("s_waitcnt vmcnt(0)" ::: "memory");  // last stage landed
            __builtin_amdgcn_s_barrier();
            __builtin_amdgcn_sched_barrier(0);
        }
    }

    // ---- fused scores (registers + shfl only) ----
    const int hh_ = ATOMIC ? 0 : (blockIdx.y * 2 + wn);
    float4 asj[4], adj[4];
    #pragma unroll
    for (int j = 0; j < 4; ++j) {
        int cb = (ATOMIC ? wn * 64 : 0) + j * 16 + quad * 4;
        asj[j] = *(const float4*)&asrc[hh_ * CD + cb];
        adj[j] = *(const float4*)&adst[hh_ * CD + cb];
    }
    #pragma unroll
    for (int i = 0; i < 4; ++i) {
        float sv = 0.f, dv = 0.f;
        #pragma unroll
        for (int j = 0; j < 4; ++j) {
            sv = fmaf(acc[i][j][0], asj[j].x, sv); dv = fmaf(acc[i][j][0], adj[j].x, dv);
            sv = fmaf(acc[i][j][1], asj[j].y, sv); dv = fmaf(acc[i][j][1], adj[j].y, dv);
            sv = fmaf(acc[i][j][2], asj[j].z, sv); dv = fmaf(acc[i][j][2], adj[j].z, dv);
            sv = fmaf(acc[i][j][3], asj[j].w, sv); dv = fmaf(acc[i][j][3], adj[j].w, dv);
        }
        sv += __shfl_xor(sv, 16, 64); dv += __shfl_xor(dv, 16, 64);
        sv += __shfl_xor(sv, 32, 64); dv += __shfl_xor(dv, 32, 64);
        int r = row0 + wm * 64 + i * 16 + cc;
        if (quad == 0 && r < M) {
            if constexpr (ATOMIC) {
                atomicAdd(&S[r], sv);
                atomicAdd(&D[r], dv);
            } else {
                S[(size_t)r * H + hh_] = sv;
                D[(size_t)r * H + hh_] = dv;
            }
        }
    }

    // ---- C store direct from registers (8B per lane per (i,j)) ----
    #pragma unroll
    for (int i = 0; i < 4; ++i) {
        int gr = row0 + wm * 64 + i * 16 + cc;
        if (gr >= M) continue;
        #pragma unroll
        for (int j = 0; j < 4; ++j) {
            int tc = col0 + wn * 64 + j * 16 + quad * 4;
            union { __half2 h2[2]; uint2 u2; } pk;
            pk.h2[0] = __floats2half2_rn(acc[i][j][0], acc[i][j][1]);
            pk.h2[1] = __floats2half2_rn(acc[i][j][2], acc[i][j][3]);
            *(uint2*)&C[(size_t)gr * N + tc] = pk.u2;
        }
    }
}

// ---------------- per-dst-node aggregation (paired-edge, 32 lanes/edge) ------
// At the gather roofline (~3.7 TB/s on random 512B granules; FETCH = compulsory
// 8 XCD x 25.6 MB). Three structurally different variants all measured
// 63.5-64.1 us -> systemic ceiling, do not touch.

template<int H, int C, bool ELU_OUT, typename OT>
__global__ __launch_bounds__(256) void aggr_k(const __half* __restrict__ xp,
                                              const float* __restrict__ s,
                                              const float* __restrict__ d,
                                              const int* __restrict__ offs,
                                              const unsigned short* __restrict__ csr,
                                              const float* __restrict__ bias,
                                              OT* __restrict__ out) {
    constexpr int HCl = H * C;
    constexpr int FPL = HCl / 32;     // halfs per lane (8 or 4)
    constexpr int U = 8;              // edges per batch (4 per parity half)
    const int tid = threadIdx.x;
    const int lane = tid & 63;
    const int l = lane & 31;          // feature-lane within half
    const int par = lane >> 5;        // edge parity of this half
    int wid = blockIdx.x * 4 + (tid >> 6);
    if (wid >= N_NODES) return;
    const int h = (l * FPL) / C;      // head of this lane (0 when H==1)
    const int loff = l * FPL;         // halfs offset within row

    float dh = d[wid * H + h];
    float z = 0.f;
    float acc[FPL];
    #pragma unroll
    for (int k = 0; k < FPL; ++k) acc[k] = 0.f;

    const int e0 = offs[wid];
    const int e1 = offs[wid + 1];

    for (int j = e0; j < e1; j += U) {
        int ss[4];
        #pragma unroll
        for (int k2 = 0; k2 < 4; ++k2) {
            int idx = j + 2 * k2 + par;
            ss[k2] = csr[idx < e1 ? idx : e1 - 1];
        }
        float ev[4];
        #pragma unroll
        for (int k2 = 0; k2 < 4; ++k2)
            ev[k2] = s[ss[k2] * H + h];
        uint4 r4[4];
        uint2 r2[4];
        #pragma unroll
        for (int k2 = 0; k2 < 4; ++k2) {
            const __half* rowp = xp + (size_t)ss[k2] * HCl + loff;
            if constexpr (FPL == 8) r4[k2] = *(const uint4*)rowp;
            else                    r2[k2] = *(const uint2*)rowp;
        }
        #pragma unroll
        for (int k2 = 0; k2 < 4; ++k2) {
            float e = (j + 2 * k2 + par < e1) ? (ev[k2] + dh) : -1e30f;
            e = fmaxf(e, 0.2f * e);          // leaky_relu
            float pw = __expf(e);            // 0 for masked slots
            z += pw;
            if constexpr (FPL == 8) {
                union { uint4 u; __half2 h2[4]; } rr; rr.u = r4[k2];
                #pragma unroll
                for (int q = 0; q < 4; ++q) {
                    acc[2*q]   = fmaf(pw, __half2float(__low2half(rr.h2[q])),  acc[2*q]);
                    acc[2*q+1] = fmaf(pw, __half2float(__high2half(rr.h2[q])), acc[2*q+1]);
                }
            } else {
                union { uint2 u; __half2 h2[2]; } rr; rr.u = r2[k2];
                #pragma unroll
                for (int q = 0; q < 2; ++q) {
                    acc[2*q]   = fmaf(pw, __half2float(__low2half(rr.h2[q])),  acc[2*q]);
                    acc[2*q+1] = fmaf(pw, __half2float(__high2half(rr.h2[q])), acc[2*q+1]);
                }
            }
        }
    }

    // merge the two parity halves (lane l and l+32 hold the same features)
    z += __shfl_xor(z, 32, 64);
    #pragma unroll
    for (int k = 0; k < FPL; ++k) acc[k] += __shfl_xor(acc[k], 32, 64);

    if (lane >= 32) return;   // lower half writes

    float inv = 1.f / (z + 1e-16f);
    float o[FPL];
    #pragma unroll
    for (int k = 0; k < FPL; ++k) {
        o[k] = acc[k] * inv + bias[loff + k];
        if constexpr (ELU_OUT) o[k] = (o[k] > 0.f) ? o[k] : (__expf(o[k]) - 1.f);
    }
    if constexpr (sizeof(OT) == 2 && FPL == 8) {
        union { __half2 h2[4]; uint4 u4; } u;
        u.h2[0] = __floats2half2_rn(o[0], o[1]);
        u.h2[1] = __floats2half2_rn(o[2], o[3]);
        u.h2[2] = __floats2half2_rn(o[4], o[5]);
        u.h2[3] = __floats2half2_rn(o[6], o[7]);
        *(uint4*)((__half*)out + (size_t)wid * HCl + loff) = u.u4;
    } else if constexpr (sizeof(OT) == 4 && FPL == 4) {
        float4 v; v.x = o[0]; v.y = o[1]; v.z = o[2]; v.w = o[3];
        *(float4*)((float*)out + (size_t)wid * HCl + loff) = v;
    } else {
        #pragma unroll
        for (int k = 0; k < FPL; ++k)
            out[(size_t)wid * HCl + loff + k] = (OT)o[k];
    }
}

// ---------------- launch ----------------

extern "C" void kernel_launch(void* const* d_in, const int* in_sizes, int n_in,
                              void* d_out, int out_size, void* d_ws, size_t ws_size,
                              hipStream_t stream) {
    const float* x      = (const float*)d_in[0];
    const int*   ei     = (const int*)  d_in[1];
    const float* W0     = (const float*)d_in[2];
    const float* as0    = (const float*)d_in[3];
    const float* ad0    = (const float*)d_in[4];
    const float* b0     = (const float*)d_in[5];
    const float* W1     = (const float*)d_in[6];
    const float* as1    = (const float*)d_in[7];
    const float* ad1    = (const float*)d_in[8];
    const float* b1     = (const float*)d_in[9];
    const float* W2     = (const float*)d_in[10];
    const float* as2    = (const float*)d_in[11];
    const float* ad2    = (const float*)d_in[12];
    const float* b2     = (const float*)d_in[13];
    float* out = (float*)d_out;

    // workspace layout (256B aligned chunks)
    char* p = (char*)d_ws;
    auto take = [&](size_t bytes) {
        char* r = p;
        p += (bytes + 255) & ~(size_t)255;
        return r;
    };
    __half* XPh   = (__half*)take((size_t)N_NODES * HC * 2);
    __half* Hbuf  = (__half*)take((size_t)N_NODES * HC * 2);
    __half* xh    = (__half*)take((size_t)N_NODES * IN_DIM * 2);
    __half* Wt0   = (__half*)take((size_t)IN_DIM * HC * 2);
    __half* Wt1   = (__half*)take((size_t)HC * HC * 2);
    __half* Wt2   = (__half*)take((size_t)HC * OUTD * 2);
    float*  S     = (float*) take((size_t)N_NODES * HEADS * 4);
    float*  D     = (float*) take((size_t)N_NODES * HEADS * 4);
    float*  S2    = (float*) take((size_t)N_NODES * 4);
    float*  D2    = (float*) take((size_t)N_NODES * 4);
    int*    counts= (int*)   take((size_t)N_NODES * 4);
    int*    offs  = (int*)   take((size_t)(N_NODES + 1) * 4);
    int*    bsums = (int*)   take(512 * 4);
    unsigned short* csr = (unsigned short*)take((size_t)ET * 2);

    const int NB_SCAN = (N_NODES + 511) / 512;   // 98
    const int ET_BLOCKS = (ET + 255) / 256;
    const int NODE_BLOCKS = (N_NODES + 3) / 4;   // 12500
    const int MB = (N_NODES + 127) / 128;        // 391
    dim3 g0(MB, HC / 128);                       // 391 x 2
    dim3 g2(MB, OUTD / 128);                     // 391 x 1

    // ---- setup: zero counts; fused hist + cvt + wtrans + zero S2/D2 ----
    hipMemsetAsync(counts, 0, (size_t)N_NODES * 4, stream);
    setup_k<<<(SETUP_TOTAL + 255) / 256, 256, 0, stream>>>(
        ei, counts, x, xh, W0, Wt0, W1, Wt1, W2, Wt2, S2, D2);

    // ---- CSR scan + fill ----
    scan1_k<<<NB_SCAN, 512, 0, stream>>>(counts, offs, bsums);
    scan3_k<<<NB_SCAN, 512, 0, stream>>>(offs, bsums);
    fill_k<<<ET_BLOCKS, 256, 0, stream>>>(ei, offs, counts, csr);

    // ---- layer 0: 128 -> 4x64, concat, ELU ----
    gemm_mfma_k<HEADS, HID, false, IN_DIM><<<g0, 256, 0, stream>>>(xh, Wt0, XPh, as0, ad0, S, D, N_NODES, HC);
    aggr_k<HEADS, HID, true, __half><<<NODE_BLOCKS, 256, 0, stream>>>(XPh, S, D, offs, csr, b0, Hbuf);

    // ---- layer 1: 256 -> 4x64, concat, ELU ----
    gemm_mfma_k<HEADS, HID, false, HC><<<g0, 256, 0, stream>>>(Hbuf, Wt1, XPh, as1, ad1, S, D, N_NODES, HC);
    aggr_k<HEADS, HID, true, __half><<<NODE_BLOCKS, 256, 0, stream>>>(XPh, S, D, offs, csr, b1, Hbuf);

    // ---- layer 2: 256 -> 1x128, mean(H=1), no ELU ----
    gemm_mfma_k<1, OUTD, true, HC><<<g2, 256, 0, stream>>>(Hbuf, Wt2, XPh, as2, ad2, S2, D2, N_NODES, OUTD);
    aggr_k<1, OUTD, false, float><<<NODE_BLOCKS, 256, 0, stream>>>(XPh, S2, D2, offs, csr, b2, out);
}